// Round 9
// baseline (317.516 us; speedup 1.0000x reference)
//
#include <hip/hip_runtime.h>
#include <math.h>

#define V 100000
#define D 128
#define A 64
#define LVLS 3
#define NN 20000
#define KK 16
#define BKP 16
#define ASTP 18      // 16 + 2 pad (proven conflict-free family: commit's AST2)
#define BSTP 132     // 128 + 4 pad (proven: R7 Bs)
#define BK2 16
#define AST2 18
#define BST2 68
#define PSTRIDE 128  // projAll row: [0,64)=node-half (W1+b), [64,128)=neighbor-half (W2)

// Plain BW-bound copy: out = Leaf. Runs first -> warms L3 with all of Leaf
// so the projection GEMM's staging reads are L3 hits.
__global__ void copy_kernel(const float* __restrict__ src, float* __restrict__ dst,
                            long long n4) {
    long long i = (long long)blockIdx.x * 256 + threadIdx.x;
    long long stride = (long long)gridDim.x * 256;
    for (; i < n4; i += stride)
        ((float4*)dst)[i] = ((const float4*)src)[i];
}

// Projection-only merged GEMM: projAll[V][128] = Leaf @ Wcomb[128][128]
// (cols 0-63 = W_att[0:128] + bias, cols 64-127 = W_att[128:256]).
// TM=128, 8x8 micro, BK=16 -> LDS 17.7 KB -> 3 blocks/CU (12 waves/CU).
// No fused copy (that's what forced BK=32 full-line writes before).
__global__ __launch_bounds__(256, 2)
void projonly_kernel(const float* __restrict__ Leaf, const float* __restrict__ Watt,
                     const float* __restrict__ batt, float* __restrict__ projAll) {
    __shared__ float As[128 * ASTP];  // 9.2 KB
    __shared__ float Bs[BKP * BSTP];  // 8.4 KB
    int t = threadIdx.x;
    int tx = t & 15, ty = t >> 4;
    int r0 = blockIdx.x * 128;

    // A staging: rows ar, ar+64; 4 threads per row (16 floats/chunk)
    int ar = t >> 2, ak = (t & 3) << 2;
    const float* asrc[2];
#pragma unroll
    for (int jj = 0; jj < 2; ++jj) {
        int r = r0 + ar + 64 * jj;
        int rr = r < V ? r : V - 1;
        asrc[jj] = Leaf + (size_t)rr * D + ak;
    }
    // B staging: row bk (0..15), cols bc (W1) and bc+64 (W2)
    int bk = t >> 4, bc = (t & 15) << 2;

    float4 bv = *(const float4*)(batt + 4 * tx);
    float accA[8][4], accB[8][4];
#pragma unroll
    for (int i = 0; i < 8; ++i) {
        accA[i][0] = bv.x; accA[i][1] = bv.y; accA[i][2] = bv.z; accA[i][3] = bv.w;
        accB[i][0] = 0.f;  accB[i][1] = 0.f;  accB[i][2] = 0.f;  accB[i][3] = 0.f;
    }

    for (int k0 = 0; k0 < D; k0 += BKP) {
        if (k0) __syncthreads();
        *(float4*)&As[(ar +  0) * ASTP + ak] = *(const float4*)(asrc[0] + k0);
        *(float4*)&As[(ar + 64) * ASTP + ak] = *(const float4*)(asrc[1] + k0);
        *(float4*)&Bs[bk * BSTP + bc] =
            *(const float4*)(Watt + (size_t)(k0 + bk) * A + bc);
        *(float4*)&Bs[bk * BSTP + 64 + bc] =
            *(const float4*)(Watt + (size_t)(128 + k0 + bk) * A + bc);
        __syncthreads();
#pragma unroll
        for (int kc = 0; kc < BKP; kc += 4) {
            float4 b0 = *(const float4*)&Bs[(kc + 0) * BSTP + 4 * tx];
            float4 b1 = *(const float4*)&Bs[(kc + 1) * BSTP + 4 * tx];
            float4 b2 = *(const float4*)&Bs[(kc + 2) * BSTP + 4 * tx];
            float4 b3 = *(const float4*)&Bs[(kc + 3) * BSTP + 4 * tx];
            float4 c0 = *(const float4*)&Bs[(kc + 0) * BSTP + 64 + 4 * tx];
            float4 c1 = *(const float4*)&Bs[(kc + 1) * BSTP + 64 + 4 * tx];
            float4 c2 = *(const float4*)&Bs[(kc + 2) * BSTP + 64 + 4 * tx];
            float4 c3 = *(const float4*)&Bs[(kc + 3) * BSTP + 64 + 4 * tx];
#pragma unroll
            for (int i = 0; i < 8; ++i) {
                float4 a = *(const float4*)&As[(8 * ty + i) * ASTP + kc];
                accA[i][0] = fmaf(a.x, b0.x, accA[i][0]);
                accA[i][0] = fmaf(a.y, b1.x, accA[i][0]);
                accA[i][0] = fmaf(a.z, b2.x, accA[i][0]);
                accA[i][0] = fmaf(a.w, b3.x, accA[i][0]);
                accA[i][1] = fmaf(a.x, b0.y, accA[i][1]);
                accA[i][1] = fmaf(a.y, b1.y, accA[i][1]);
                accA[i][1] = fmaf(a.z, b2.y, accA[i][1]);
                accA[i][1] = fmaf(a.w, b3.y, accA[i][1]);
                accA[i][2] = fmaf(a.x, b0.z, accA[i][2]);
                accA[i][2] = fmaf(a.y, b1.z, accA[i][2]);
                accA[i][2] = fmaf(a.z, b2.z, accA[i][2]);
                accA[i][2] = fmaf(a.w, b3.z, accA[i][2]);
                accA[i][3] = fmaf(a.x, b0.w, accA[i][3]);
                accA[i][3] = fmaf(a.y, b1.w, accA[i][3]);
                accA[i][3] = fmaf(a.z, b2.w, accA[i][3]);
                accA[i][3] = fmaf(a.w, b3.w, accA[i][3]);
                accB[i][0] = fmaf(a.x, c0.x, accB[i][0]);
                accB[i][0] = fmaf(a.y, c1.x, accB[i][0]);
                accB[i][0] = fmaf(a.z, c2.x, accB[i][0]);
                accB[i][0] = fmaf(a.w, c3.x, accB[i][0]);
                accB[i][1] = fmaf(a.x, c0.y, accB[i][1]);
                accB[i][1] = fmaf(a.y, c1.y, accB[i][1]);
                accB[i][1] = fmaf(a.z, c2.y, accB[i][1]);
                accB[i][1] = fmaf(a.w, c3.y, accB[i][1]);
                accB[i][2] = fmaf(a.x, c0.z, accB[i][2]);
                accB[i][2] = fmaf(a.y, c1.z, accB[i][2]);
                accB[i][2] = fmaf(a.z, c2.z, accB[i][2]);
                accB[i][2] = fmaf(a.w, c3.z, accB[i][2]);
                accB[i][3] = fmaf(a.x, c0.w, accB[i][3]);
                accB[i][3] = fmaf(a.y, c1.w, accB[i][3]);
                accB[i][3] = fmaf(a.z, c2.w, accB[i][3]);
                accB[i][3] = fmaf(a.w, c3.w, accB[i][3]);
            }
        }
    }

#pragma unroll
    for (int i = 0; i < 8; ++i) {
        int gr = r0 + 8 * ty + i;
        if (gr < V) {
            float4 oA = make_float4(accA[i][0], accA[i][1], accA[i][2], accA[i][3]);
            float4 oB = make_float4(accB[i][0], accB[i][1], accB[i][2], accB[i][3]);
            *(float4*)(projAll + (size_t)gr * PSTRIDE + 4 * tx) = oA;
            *(float4*)(projAll + (size_t)gr * PSTRIDE + 64 + 4 * tx) = oB;
        }
    }
}

// Fused scatter (winner rows tmp -> out) + bottom-half proj refresh (R2-R8 passed).
__global__ __launch_bounds__(256, 4)
void commit_kernel(const float* __restrict__ tmp, const float* __restrict__ Wmat,
                   const int* __restrict__ nodes_l, const int* __restrict__ claim,
                   float* __restrict__ outp, float* __restrict__ projAll, int do_proj) {
    __shared__ float As[64 * AST2];   // 4.6 KB
    __shared__ float Bs[BK2 * BST2];  // 4.4 KB
    int t = threadIdx.x;
    int tx = t & 15, ty = t >> 4;
    int r0 = blockIdx.x * 64;

    int ar = t >> 2;
    int ak = (t & 3) << 2;
    int r = r0 + ar;
    int rr = r < NN ? r : NN - 1;
    const float* asrc = tmp + (size_t)rr * D + ak;
    int vrow = nodes_l[rr];
    int win = (r < NN) && (claim[vrow] == rr);   // last-occurrence-wins

    int bk = t >> 4;
    int bc = (t & 15) << 2;

    float acc[4][4];
#pragma unroll
    for (int i = 0; i < 4; ++i) {
        acc[i][0] = 0.f; acc[i][1] = 0.f; acc[i][2] = 0.f; acc[i][3] = 0.f;
    }

    float4 pa = *(const float4*)(asrc);
    float4 pb = make_float4(0.f, 0.f, 0.f, 0.f);
    if (do_proj) pb = *(const float4*)(Wmat + (size_t)bk * A + bc);

    for (int k0 = 0; k0 < D; k0 += BK2) {
        if (k0) __syncthreads();
        *(float4*)&As[ar * AST2 + ak] = pa;
        if (do_proj) *(float4*)&Bs[bk * BST2 + bc] = pb;
        if (win)
            *(float4*)(outp + (size_t)vrow * D + k0 + ak) = pa;
        __syncthreads();
        int kn = k0 + BK2;
        if (kn < D) {
            pa = *(const float4*)(asrc + kn);
            if (do_proj) pb = *(const float4*)(Wmat + (size_t)(kn + bk) * A + bc);
        }
        if (do_proj) {
#pragma unroll
            for (int kc = 0; kc < BK2; kc += 4) {
                float4 b0 = *(const float4*)&Bs[(kc + 0) * BST2 + 4 * tx];
                float4 b1 = *(const float4*)&Bs[(kc + 1) * BST2 + 4 * tx];
                float4 b2 = *(const float4*)&Bs[(kc + 2) * BST2 + 4 * tx];
                float4 b3 = *(const float4*)&Bs[(kc + 3) * BST2 + 4 * tx];
#pragma unroll
                for (int i = 0; i < 4; ++i) {
                    float4 a = *(const float4*)&As[(4 * ty + i) * AST2 + kc];
                    acc[i][0] = fmaf(a.x, b0.x, acc[i][0]);
                    acc[i][0] = fmaf(a.y, b1.x, acc[i][0]);
                    acc[i][0] = fmaf(a.z, b2.x, acc[i][0]);
                    acc[i][0] = fmaf(a.w, b3.x, acc[i][0]);
                    acc[i][1] = fmaf(a.x, b0.y, acc[i][1]);
                    acc[i][1] = fmaf(a.y, b1.y, acc[i][1]);
                    acc[i][1] = fmaf(a.z, b2.y, acc[i][1]);
                    acc[i][1] = fmaf(a.w, b3.y, acc[i][1]);
                    acc[i][2] = fmaf(a.x, b0.z, acc[i][2]);
                    acc[i][2] = fmaf(a.y, b1.z, acc[i][2]);
                    acc[i][2] = fmaf(a.z, b2.z, acc[i][2]);
                    acc[i][2] = fmaf(a.w, b3.z, acc[i][2]);
                    acc[i][3] = fmaf(a.x, b0.w, acc[i][3]);
                    acc[i][3] = fmaf(a.y, b1.w, acc[i][3]);
                    acc[i][3] = fmaf(a.z, b2.w, acc[i][3]);
                    acc[i][3] = fmaf(a.w, b3.w, acc[i][3]);
                }
            }
        }
    }

    if (do_proj) {
#pragma unroll
        for (int i = 0; i < 4; ++i) {
            int gr = r0 + 4 * ty + i;
            if (gr < NN) {
                int v = nodes_l[gr];
                if (claim[v] == gr) {
                    float4 o = make_float4(acc[i][0], acc[i][1], acc[i][2], acc[i][3]);
                    *(float4*)(projAll + (size_t)v * PSTRIDE + 64 + 4 * tx) = o;
                }
            }
        }
    }
}

// One wave per node (R7-proven form: 4 nodes/block, hoisted PV gathers).
__global__ __launch_bounds__(256)
void attn_kernel(const float* __restrict__ Wc, const float* __restrict__ projAll,
                 const int* __restrict__ nodes_l, const int* __restrict__ neigh,
                 const float* __restrict__ maskp, const float* __restrict__ weightp,
                 const float* __restrict__ v_att, float* __restrict__ tmp) {
    int lane = threadIdx.x & 63;
    int n = blockIdx.x * 4 + (threadIdx.x >> 6);
    int k16 = lane & 15, q = lane >> 4;

    int   vnode = nodes_l[n];
    int   nbk = neigh[n * KK + k16];
    float wv  = weightp[n * KK + k16];
    float mk  = maskp[n * KK + k16];

    const float* npr = projAll + (size_t)vnode * PSTRIDE + q * 16;
    const float* var = v_att + q * 16;
    const float* pr  = projAll + (size_t)nbk * PSTRIDE + 64 + q * 16;

    float part = 0.f;
#pragma unroll
    for (int j = 0; j < 16; j += 4) {
        float4 npv = *(const float4*)(npr + j);
        float4 vav = *(const float4*)(var + j);
        float4 pv  = *(const float4*)(pr + j);
        float x;
        x = npv.x + pv.x; x = fmaxf(x, 0.01f * x); part = fmaf(x, vav.x, part);
        x = npv.y + pv.y; x = fmaxf(x, 0.01f * x); part = fmaf(x, vav.y, part);
        x = npv.z + pv.z; x = fmaxf(x, 0.01f * x); part = fmaf(x, vav.z, part);
        x = npv.w + pv.w; x = fmaxf(x, 0.01f * x); part = fmaf(x, vav.w, part);
    }
    part += __shfl_xor(part, 16);
    part += __shfl_xor(part, 32);
    float pre = part + mk;

    // hoisted PV gathers (independent of att)
    int half = lane >> 5, li = lane & 31;
    float4 e[8];
#pragma unroll
    for (int m = 0; m < 8; ++m) {
        int nb = __shfl(nbk, 2 * m + half);
        e[m] = *(const float4*)&Wc[(size_t)nb * D + 4 * li];
    }

    float mp = pre, mw = wv;
#pragma unroll
    for (int off = 8; off >= 1; off >>= 1) {
        mp = fmaxf(mp, __shfl_xor(mp, off));
        mw = fmaxf(mw, __shfl_xor(mw, off));
    }
    float ep = __expf(pre - mp), ew = __expf(wv - mw);
    float sp = ep, sw = ew;
#pragma unroll
    for (int off = 8; off >= 1; off >>= 1) {
        sp += __shfl_xor(sp, off);
        sw += __shfl_xor(sw, off);
    }
    float att = (ep / sp) * (ew / sw);

    float ax = 0.f, ay = 0.f, az = 0.f, aw = 0.f;
#pragma unroll
    for (int m = 0; m < 8; ++m) {
        float ak = __shfl(att, 2 * m + half);
        ax = fmaf(e[m].x, ak, ax); ay = fmaf(e[m].y, ak, ay);
        az = fmaf(e[m].z, ak, az); aw = fmaf(e[m].w, ak, aw);
    }
    ax += __shfl_xor(ax, 32); ay += __shfl_xor(ay, 32);
    az += __shfl_xor(az, 32); aw += __shfl_xor(aw, 32);
    if (half == 0) {
        float4 o = make_float4(ax, ay, az, aw);
        *(float4*)&tmp[(size_t)n * D + 4 * li] = o;
    }
}

// claims for ALL levels in one pass (depends only on nodes input)
__global__ void amax3_kernel(const int* __restrict__ nodes, int* __restrict__ claims, int total) {
    int i = blockIdx.x * 256 + threadIdx.x;
    if (i < total) {
        int lvl = i / NN, pos = i - lvl * NN;
        atomicMax(&claims[(size_t)lvl * V + nodes[i]], pos);
    }
}

extern "C" void kernel_launch(void* const* d_in, const int* in_sizes, int n_in,
                              void* d_out, int out_size, void* d_ws, size_t ws_size,
                              hipStream_t stream) {
    const float* Leaf    = (const float*)d_in[0];
    const int*   nodes   = (const int*)d_in[1];
    const int*   neigh   = (const int*)d_in[2];
    const float* masks   = (const float*)d_in[3];
    const float* weights = (const float*)d_in[4];
    const float* Watt    = (const float*)d_in[5];
    const float* batt    = (const float*)d_in[6];
    const float* vatt    = (const float*)d_in[7];
    float* out = (float*)d_out;

    char* ws = (char*)d_ws;
    float* projAll = (float*)ws;                                      // V*128
    float* tmp     = (float*)(ws + (size_t)V * PSTRIDE * 4);          // NN*D
    int*   claims  = (int*)(ws + (size_t)(V * PSTRIDE + NN * D) * 4); // LVLS*V

    hipMemsetAsync(claims, 0xFF, (size_t)LVLS * V * sizeof(int), stream);  // -1
    amax3_kernel<<<(LVLS * NN + 255) / 256, 256, 0, stream>>>(nodes, claims, LVLS * NN);
    // copy first: BW-bound, and warms L3 with Leaf for the GEMM's staging reads
    copy_kernel<<<2048, 256, 0, stream>>>(Leaf, out, (long long)V * D / 4);
    projonly_kernel<<<(V + 127) / 128, 256, 0, stream>>>(Leaf, Watt, batt, projAll);

    for (int l = 0; l < LVLS; ++l) {
        const int* nodes_l = nodes + l * NN;
        attn_kernel<<<NN / 4, 256, 0, stream>>>(out, projAll, nodes_l,
                                                neigh + (size_t)l * NN * KK,
                                                masks + (size_t)l * NN * KK,
                                                weights + (size_t)l * NN * KK, vatt, tmp);
        commit_kernel<<<(NN + 63) / 64, 256, 0, stream>>>(
            tmp, Watt + (size_t)D * A, nodes_l, claims + (size_t)l * V, out, projAll,
            (l + 1 < LVLS) ? 1 : 0);
    }
}